// Round 13
// baseline (65.741 us; speedup 1.0000x reference)
//
#include <hip/hip_runtime.h>
#include <math.h>

#define WID 48
#define HW 2304
#define PAD 50

typedef _Float16 half8 __attribute__((ext_vector_type(8)));
typedef _Float16 half2 __attribute__((ext_vector_type(2)));
typedef float f32x4 __attribute__((ext_vector_type(4)));

__device__ __forceinline__ void gload_lds16(const void* g, void* l) {
  __builtin_amdgcn_global_load_lds((const __attribute__((address_space(1))) void*)g,
                                   (__attribute__((address_space(3))) void*)l, 16, 0, 0);
}

// ---------------------------------------------------------------------------
// Merged prep kernel: four independent jobs dispatched by blockIdx.x range.
//   [0, 576)      pad+transpose+f16 convert (LDS-transpose, coalesced both sides)
//   [576, 3024)   weight transform OIHW f32 -> [row][tap*128+ci] f16
//   [3024, 3325)  border zero of 24 padded buffer-images + guard rows
//   [3325, 3343)  flow-guided offset adds
// ---------------------------------------------------------------------------
__global__ __launch_bounds__(256) void prep_kernel(
    const float* __restrict__ q, const float* __restrict__ f,
    _Float16* __restrict__ xq, _Float16* __restrict__ xf,
    const float* __restrict__ wv, const float* __restrict__ wo,
    const float* __restrict__ wa, const float* __restrict__ wu,
    _Float16* __restrict__ wt,
    const float* __restrict__ ff, const float* __restrict__ fb,
    float* __restrict__ adds,
    _Float16* __restrict__ wsh) {
  __shared__ _Float16 plds[48 * 136];      // [px][c], stride 136: bank decorrelation
  const int b = blockIdx.x;
  const int tid = threadIdx.x;

  if (b < 576) {
    // ---- pad_convert: one block per (buf, img, image-row) ----
    const int buf = b / 288;
    const int rem = b - buf * 288;
    const int img = rem / 48, y = rem - img * 48;
    const float* src = buf ? f : q;
    _Float16* dst = buf ? xf : xq;

    const int c = tid >> 1;                // channel 0..127
    const int seg = tid & 1;               // pixel half: 0..23 / 24..47
    const float* rowp = src + ((size_t)img * 128 + c) * HW + y * WID + seg * 24;
    f32x4 v[6];
#pragma unroll
    for (int k = 0; k < 6; ++k) v[k] = *(const f32x4*)(rowp + 4 * k);
#pragma unroll
    for (int k = 0; k < 6; ++k)
#pragma unroll
      for (int e = 0; e < 4; ++e)
        plds[(seg * 24 + 4 * k + e) * 136 + c] = (_Float16)v[k][e];
    __syncthreads();

    _Float16* dstp = dst + (((size_t)img * PAD + y + 1) * PAD + 1) * 128;
#pragma unroll
    for (int k = 0; k < 3; ++k) {
      int m = tid + 256 * k;               // chunk 0..767
      int px = m >> 4, c0 = (m & 15) << 3;
      half8 h = *(const half8*)(plds + px * 136 + c0);
      *(half8*)(dstp + (size_t)m * 8) = h;
    }

  } else if (b < 3024) {
    // ---- weight transform ----
    int gi = (b - 576) * 256 + tid;
    if (gi >= 544 * 1152) return;
    int row = gi / 1152, k = gi - row * 1152;
    int tap = k >> 7, ci = k & 127;
    const float* src; int co;
    if (row < 128)      { src = wv; co = row; }
    else if (row < 320) { src = wo; co = row - 128; }
    else if (row < 416) { src = wa; co = row - 320; }
    else                { src = wu; co = row - 416; }
    wt[gi] = (_Float16)src[((size_t)co * 128 + ci) * 9 + tap];

  } else if (b < 3325) {
    // ---- border zero ----
    int gi = (b - 3024) * 256 + tid;
    const int IMG_ELE = PAD * PAD * 128;     // 320000 halfs per padded image
    half8 z = {};
    if (gi < 75264) {
      int bi = gi / 3136;                    // buffer-image 0..23
      int r = gi - bi * 3136;
      int p = r >> 4;                        // border pixel 0..195
      int cc = (r & 15) << 3;                // half offset within 128
      int y, x;
      if (p < 50)       { y = 0;           x = p; }
      else if (p < 100) { y = 49;          x = p - 50; }
      else if (p < 148) { y = p - 100 + 1; x = 0; }
      else              { y = p - 148 + 1; x = 49; }
      *(half8*)(wsh + (size_t)bi * IMG_ELE + ((size_t)y * PAD + x) * 128 + cc) = z;
    } else if (gi < 76864) {
      int r = gi - 75264;                    // guard: 2 rows of 50 px
      *(half8*)(wsh + (size_t)24 * IMG_ELE + (size_t)r * 8) = z;
    }

  } else {
    // ---- flow adds ----
    int idx = (b - 3325) * 256 + tid;
    if (idx >= 2 * HW) return;
    int n = idx / HW, hw = idx - n * HW;
    int y = hw / WID, x = hw - y * WID;

    const float* F = ff + (size_t)n * 4 * HW;
    const float* B = fb + (size_t)n * 4 * HW;

    float ff01x = F[hw],          ff01y = F[HW + hw];
    float ff12x = F[2 * HW + hw], ff12y = F[3 * HW + hw];
    float fb10x = B[hw],          fb10y = B[HW + hw];
    float fb21x = B[2 * HW + hw], fb21y = B[3 * HW + hw];

    auto warp2 = [&](const float* cx, const float* cy, float flox, float floy,
                     float& ox, float& oy) {
      float sx = (float)x + flox, sy = (float)y + floy;
      float fx = floorf(sx), fy = floorf(sy);
      int x0 = (int)fx, y0 = (int)fy;
      float wx = sx - fx, wy = sy - fy;
      float w00 = (1.f - wx) * (1.f - wy), w10 = wx * (1.f - wy);
      float w01 = (1.f - wx) * wy,         w11 = wx * wy;
      auto inside = [](int xi, int yi) {
        return (xi >= 0 && xi <= WID - 1 && yi >= 0 && yi <= WID - 1) ? 1.f : 0.f;
      };
      float m = w00 * inside(x0, y0)     + w10 * inside(x0 + 1, y0) +
                w01 * inside(x0, y0 + 1) + w11 * inside(x0 + 1, y0 + 1);
      float mm = (m < 0.999f) ? 0.f : 1.f;
      auto cl = [](int v) { return v < 0 ? 0 : (v > WID - 1 ? WID - 1 : v); };
      int xa = cl(x0), xb = cl(x0 + 1), ya = cl(y0), yb = cl(y0 + 1);
      int i00 = ya * WID + xa, i10 = ya * WID + xb;
      int i01 = yb * WID + xa, i11 = yb * WID + xb;
      ox = mm * (w00 * cx[i00] + w10 * cx[i10] + w01 * cx[i01] + w11 * cx[i11]);
      oy = mm * (w00 * cy[i00] + w10 * cy[i10] + w01 * cy[i01] + w11 * cy[i11]);
    };

    float wfx, wfy;
    warp2(F + 2 * HW, F + 3 * HW, ff01x, ff01y, wfx, wfy);
    float ff02x = ff01x + wfx, ff02y = ff01y + wfy;
    float wbx, wby;
    warp2(B, B + HW, fb21x, fb21y, wbx, wby);
    float fb20x = fb21x + wbx, fb20y = fb21y + wby;

    auto W_ = [&](int t, int l, float vx, float vy) {
      size_t o = (((size_t)(n * 3 + t) * 3 + l) * HW + hw) * 2;
      adds[o] = vx; adds[o + 1] = vy;
    };
    W_(0, 0, 0.f, 0.f);     W_(0, 1, ff01x, ff01y); W_(0, 2, ff02x, ff02y);
    W_(1, 0, fb10x, fb10y); W_(1, 1, 0.f, 0.f);     W_(1, 2, ff12x, ff12y);
    W_(2, 0, fb20x, fb20y); W_(2, 1, fb21x, fb21y); W_(2, 2, 0.f, 0.f);
  }
}

// ---------------------------------------------------------------------------
// MFMA implicit-GEMM conv body, 2-deep COUNTED-VMCNT pipeline (T3/T4, m201
// template form): raw s_barrier (no implicit vmcnt(0) drain) + inline-asm
// s_waitcnt vmcnt(5). 2 buffers x 20KB keeps 3 blocks/CU. (r10-verified.)
// ---------------------------------------------------------------------------
#define CONV_BUF_ELE (96 * 64 + 64 * 64)   // 10240 halfs per buffer

__device__ __forceinline__ void conv_body(
    int bx, const _Float16* __restrict__ xpad, const _Float16* __restrict__ wt,
    const float* __restrict__ bias0, const float* __restrict__ bias1, int bsplit,
    int CO, int co0, int layout, void* __restrict__ outp, _Float16* lds) {
  const int tid = threadIdx.x;
  const int w = tid >> 6, lane = tid & 63;
  const int img = bx / 24, rp = bx - img * 24;
  const int y0 = rp * 2;

  const int pxh = w & 1, coh = w >> 1;

  f32x4 acc[3][2] = {};

  const int lr8 = lane >> 3;               // 0..7
  const int lc  = lane & 7;                // chunk 0..7

  // stage s: 5 global_load_lds per wave (3 A + 2 B) into buffer l
  auto stage = [&](int s, _Float16* l) {
    const int tap = s >> 1, ci0 = (s & 1) << 6;
    const int dy = tap / 3, dx = tap - dy * 3;
    _Float16* lA = l;
    _Float16* lB = l + 96 * 64;
#pragma unroll
    for (int it = 0; it < 3; ++it) {
      int i = w * 3 + it;
      int r = 8 * i + lr8;                 // px row 0..95
      int cs = lc ^ (r & 7);
      int up = (r >= 48) ? 1 : 0;
      int yy = y0 + up + dy;
      int xx = (r - 48 * up) + dx;
      const _Float16* src = xpad + (((size_t)(img * PAD + yy)) * PAD + xx) * 128 + ci0 + cs * 8;
      gload_lds16(src, lA + i * 512);
    }
#pragma unroll
    for (int jt = 0; jt < 2; ++jt) {
      int j = w * 2 + jt;
      int r = 8 * j + lr8;                 // co row 0..63
      int cs = lc ^ (r & 7);
      int co = co0 + r; if (co >= CO) co = CO - 1;
      const _Float16* src = wt + (size_t)co * 1152 + tap * 128 + ci0 + cs * 8;
      gload_lds16(src, lB + j * 512);
    }
  };

  // prologue: stages 0 and 1 in flight; wait only stage 0 (own 5 oldest)
  stage(0, lds);
  stage(1, lds + CONV_BUF_ELE);
  asm volatile("s_waitcnt vmcnt(5)" ::: "memory");
  __builtin_amdgcn_s_barrier();

  const int lrow = lane & 15, lk = lane >> 4;
#pragma unroll
  for (int s = 0; s < 18; ++s) {
    _Float16* lA = lds + (s & 1) * CONV_BUF_ELE;   // static (unrolled)
    _Float16* lB = lA + 96 * 64;

    __builtin_amdgcn_s_setprio(1);
#pragma unroll
    for (int sub = 0; sub < 2; ++sub) {
      int kc = sub * 4 + lk;               // chunk 0..7
      half8 a[3], bb[2];
#pragma unroll
      for (int m = 0; m < 3; ++m) {
        int r = 48 * pxh + 16 * m + lrow;
        a[m] = *(const half8*)(lA + r * 64 + ((kc ^ (r & 7)) * 8));
      }
#pragma unroll
      for (int n = 0; n < 2; ++n) {
        int r = 32 * coh + 16 * n + lrow;
        bb[n] = *(const half8*)(lB + r * 64 + ((kc ^ (r & 7)) * 8));
      }
#pragma unroll
      for (int m = 0; m < 3; ++m)
#pragma unroll
        for (int n = 0; n < 2; ++n)
          acc[m][n] = __builtin_amdgcn_mfma_f32_16x16x32_f16(a[m], bb[n], acc[m][n], 0, 0, 0);
    }
    __builtin_amdgcn_s_setprio(0);

    if (s < 17) {
      __builtin_amdgcn_s_barrier();        // all waves done reading buf(s&1)
      if (s + 2 < 18) {
        stage(s + 2, lA);                  // overwrite it for stage s+2
        // wait own stage-(s+1) loads (5 oldest); s+2's 5 stay in flight
        asm volatile("s_waitcnt vmcnt(5)" ::: "memory");
      } else {
        asm volatile("s_waitcnt vmcnt(0)" ::: "memory");
      }
      __builtin_amdgcn_s_barrier();        // buf((s+1)&1) fully populated
    }
  }

  // ---- epilogue (direct stores) ----
  const int lg = lane >> 4;
#pragma unroll
  for (int m = 0; m < 3; ++m) {
#pragma unroll
    for (int n = 0; n < 2; ++n) {
      int co = co0 + 32 * coh + 16 * n + lrow;
      if (co >= CO) continue;
      float bv = (co < bsplit) ? bias0[co] : bias1[co - bsplit];
#pragma unroll
      for (int r = 0; r < 4; ++r) {
        int pl = 48 * pxh + 16 * m + 4 * lg + r;   // 0..95
        int pix = rp * 96 + pl;
        float v = acc[m][n][r] + bv;
        if (layout == 1) {
          ((_Float16*)outp)[((size_t)img * HW + pix) * CO + co] = (_Float16)v;
        } else if (layout == 2) {
          int yy = pix / WID, xx = pix - yy * WID;
          ((_Float16*)outp)[(((size_t)img * PAD + yy + 1) * PAD + xx + 1) * 128 + co] = (_Float16)v;
        } else {
          ((float*)outp)[((size_t)img * CO + co) * HW + pix] = v;
        }
      }
    }
  }
}

// Merged offattn conv (blockIdx.y 0..4) + value conv (blockIdx.y 5..6).
__global__ __launch_bounds__(256) void conv_offattn_value(
    const _Float16* __restrict__ xq, const _Float16* __restrict__ xf,
    const _Float16* __restrict__ wt,
    const float* __restrict__ b_off, const float* __restrict__ b_attn,
    const float* __restrict__ b_val,
    _Float16* __restrict__ offattn, _Float16* __restrict__ vpad) {
  __shared__ _Float16 lds[2 * CONV_BUF_ELE];
  const int y = blockIdx.y;
  if (y < 5) {
    conv_body(blockIdx.x, xq, wt + (size_t)128 * 1152, b_off, b_attn, 192,
              288, y * 64, 1, offattn, lds);
  } else {
    conv_body(blockIdx.x, xf, wt, b_val, b_val, 128,
              128, (y - 5) * 64, 2, vpad, lds);
  }
}

// Final conv: f32 NCHW out.
__global__ __launch_bounds__(256) void conv_out(
    const _Float16* __restrict__ xout, const _Float16* __restrict__ wt,
    const float* __restrict__ b_out, float* __restrict__ out) {
  __shared__ _Float16 lds[2 * CONV_BUF_ELE];
  conv_body(blockIdx.x, xout, wt, b_out, b_out, 128, 128, blockIdx.y * 64, 0,
            out, lds);
}

// ---------------------------------------------------------------------------
// Sampling + softmax + attention-weighted sum. 4 pixels per block.
// Phase 1 (x2 passes): 16-lane groups compute per-point weights/base, stage
// to LDS. Phase 2: 32 groups of 8 lanes; each lane gathers TWO channels per
// corner via one half2 (4B) load -- halves the VMEM instruction count that
// bound the old kernel; fma_mix keeps VALU per pixel unchanged.
// ---------------------------------------------------------------------------
__global__ __launch_bounds__(256) void sample_kernel(
    const _Float16* __restrict__ vpad,     // [6][50][50][128] padded values
    const _Float16* __restrict__ offattn,  // [6][hw][288] (192 off + 96 attn)
    const float* __restrict__ refpts, const float* __restrict__ adds,
    _Float16* __restrict__ xout) {
  __shared__ float Wlds[4][8][13][4];      // [pixslot][head][point(13=pad)][w]
  __shared__ int   IBlds[4][8][12];
  const int tid = threadIdx.x;

  // -------- phase 1: two passes, 2 pixels each (16-lane groups) --------
#pragma unroll
  for (int p = 0; p < 2; ++p) {
    const int ps = 2 * p + (tid >> 7);     // pixel slot 0..3
    const int h = (tid >> 4) & 7;
    const int d = tid & 15;
    const int pixg = blockIdx.x * 4 + ps;
    const int img = pixg / HW, hw = pixg - img * HW;
    const int n = img / 3, t = img - n * 3;

    const _Float16* rec = offattn + ((size_t)img * HW + hw) * 288;

    const int i = (d < 12) ? d : 11;       // lanes 12-15 duplicate point 11
    const int l = i >> 2;                  // level

    half2 o2 = *(const half2*)(rec + (h * 12 + i) * 2);
    float lgt = (float)rec[192 + h * 12 + i];
    if (d >= 12) lgt = -1e30f;

    const float* addp = adds + (((size_t)(n * 3 + t) * 3 + l) * HW + hw) * 2;
    const float* rp = refpts + ((size_t)(n * 3 + t) * HW + hw) * 6 + l * 2;

    // px = (refx + ox/48)*48 - 0.5  ==  refx*48 - 0.5 + ox   (exact algebra)
    float px = fmaf(rp[0], 48.f, -0.5f) + (float)o2[0] + addp[0];
    float py = fmaf(rp[1], 48.f, -0.5f) + (float)o2[1] + addp[1];
    // clamp into padded-border range: reproduces zeros_pad masking exactly
    px = fminf(fmaxf(px, -1.f), 48.f);
    py = fminf(fmaxf(py, -1.f), 48.f);
    float fx = floorf(px), fy = floorf(py);
    int x0 = (int)fx, y0 = (int)fy;
    float wx = px - fx, wy = py - fy;
    float w00 = (1.f - wx) * (1.f - wy), w10 = wx * (1.f - wy);
    float w01 = (1.f - wx) * wy,         w11 = wx * wy;

    // softmax over the 12 points of this (pix,h), reduced across the group
    float mx = lgt;
#pragma unroll
    for (int m = 8; m >= 1; m >>= 1) mx = fmaxf(mx, __shfl_xor(mx, m, 16));
    float e = __expf(lgt - mx);            // lanes 12-15 -> exp(-huge) = 0
    float s = e;
#pragma unroll
    for (int m = 8; m >= 1; m >>= 1) s += __shfl_xor(s, m, 16);
    float aw = e * __builtin_amdgcn_rcpf(s);
    w00 *= aw; w10 *= aw; w01 *= aw; w11 *= aw;

    // corner base index (f16 elements) into padded value image (n*3 + l)
    int ib = (((n * 3 + l) * PAD + (y0 + 1)) * PAD + (x0 + 1)) * 128 + h * 16;

    if (d < 12) {                          // lanes 12-15 must NOT write
      f32x4 w4 = {w00, w10, w01, w11};
      *(f32x4*)&Wlds[ps][h][d][0] = w4;
      IBlds[ps][h][d] = ib;
    }
  }
  __syncthreads();

  // -------- phase 2: 8-lane groups, 2 channels per lane --------
  const int g2 = tid >> 3;                 // 0..31
  const int ps2 = g2 >> 3;                 // pixel slot 0..3
  const int h2 = g2 & 7;
  const int d2 = tid & 7;                  // channel pair 0..7
  const int pixg2 = blockIdx.x * 4 + ps2;
  const int img2 = pixg2 / HW, hw2 = pixg2 - img2 * HW;

  float acc0 = 0.f, acc1 = 0.f;
#pragma unroll
  for (int j = 0; j < 12; ++j) {
    f32x4 W = *(const f32x4*)&Wlds[ps2][h2][j][0];   // broadcast read
    int jb = IBlds[ps2][h2][j];
    const _Float16* vp = vpad + jb + 2 * d2;
    half2 v00 = *(const half2*)(vp);
    half2 v10 = *(const half2*)(vp + 128);
    half2 v01 = *(const half2*)(vp + PAD * 128);
    half2 v11 = *(const half2*)(vp + PAD * 128 + 128);
    acc0 = fmaf(W[0], (float)v00[0], acc0);
    acc1 = fmaf(W[0], (float)v00[1], acc1);
    acc0 = fmaf(W[1], (float)v10[0], acc0);
    acc1 = fmaf(W[1], (float)v10[1], acc1);
    acc0 = fmaf(W[2], (float)v01[0], acc0);
    acc1 = fmaf(W[2], (float)v01[1], acc1);
    acc0 = fmaf(W[3], (float)v11[0], acc0);
    acc1 = fmaf(W[3], (float)v11[1], acc1);
  }

  int y = hw2 / WID, x = hw2 - y * WID;
  half2 o = { (_Float16)acc0, (_Float16)acc1 };
  *(half2*)(xout + (((size_t)img2 * PAD + y + 1) * PAD + x + 1) * 128 +
            h2 * 16 + 2 * d2) = o;
}

// ---------------------------------------------------------------------------
extern "C" void kernel_launch(void* const* d_in, const int* in_sizes, int n_in,
                              void* d_out, int out_size, void* d_ws, size_t ws_size,
                              hipStream_t stream) {
  const float* query         = (const float*)d_in[0];
  const float* input_flatten = (const float*)d_in[1];
  const float* refpts        = (const float*)d_in[2];
  const float* ff            = (const float*)d_in[3];
  const float* fb            = (const float*)d_in[4];
  const float* w_off         = (const float*)d_in[5];
  const float* b_off         = (const float*)d_in[6];
  const float* w_attn        = (const float*)d_in[7];
  const float* b_attn        = (const float*)d_in[8];
  const float* w_val         = (const float*)d_in[9];
  const float* b_val         = (const float*)d_in[10];
  const float* w_out         = (const float*)d_in[11];
  const float* b_out         = (const float*)d_in[12];
  float* out = (float*)d_out;

  char* ws = (char*)d_ws;
  const size_t PADSZ = (size_t)6 * PAD * PAD * 128 * sizeof(_Float16);  // 3,840,000
  const size_t GUARD = (size_t)2 * PAD * 128 * sizeof(_Float16);        // 25,600
  _Float16* xq      = (_Float16*)(ws);
  _Float16* xf      = (_Float16*)(ws + PADSZ);
  _Float16* xout    = (_Float16*)(ws + 2 * PADSZ);
  _Float16* vpad    = (_Float16*)(ws + 3 * PADSZ);                      // padded values
  _Float16* wt      = (_Float16*)(ws + 4 * PADSZ + GUARD);              // 544*1152*2
  _Float16* offattn = (_Float16*)(ws + 4 * PADSZ + GUARD + 1253376);    // 6*2304*288*2
  float*    adds    = (float*)   (ws + 4 * PADSZ + GUARD + 1253376 + 7962624);

  // 1: all independent prep work (pad/convert, weights, border zero, flow)
  prep_kernel<<<3343, 256, 0, stream>>>(query, input_flatten, xq, xf,
                                        w_val, w_off, w_attn, w_out, wt,
                                        ff, fb, adds, (_Float16*)ws);

  // 2: merged off+attn conv (y 0..4, CO=288, f16 pixel-major) and
  //    value conv (y 5..6, CO=128, f16 padded pixel-major)
  conv_offattn_value<<<dim3(144, 7), 256, 0, stream>>>(xq, xf, wt,
                                                       b_off, b_attn, b_val,
                                                       offattn, vpad);

  // 3: sampling + softmax + weighted sum (4 pixels per block)
  sample_kernel<<<3456, 256, 0, stream>>>(vpad, offattn, refpts, adds, xout);

  // 4: final conv, f32 NCHW out
  conv_out<<<dim3(144, 2), 256, 0, stream>>>(xout, wt + (size_t)416 * 1152,
                                             b_out, out);
}

// Round 15
// 65.052 us; speedup vs baseline: 1.0106x; 1.0106x over previous
//
#include <hip/hip_runtime.h>
#include <math.h>

#define WID 48
#define HW 2304
#define PAD 50

typedef _Float16 half8 __attribute__((ext_vector_type(8)));
typedef _Float16 half2 __attribute__((ext_vector_type(2)));
typedef float f32x4 __attribute__((ext_vector_type(4)));

__device__ __forceinline__ void gload_lds16(const void* g, void* l) {
  __builtin_amdgcn_global_load_lds((const __attribute__((address_space(1))) void*)g,
                                   (__attribute__((address_space(3))) void*)l, 16, 0, 0);
}

// ---------------------------------------------------------------------------
// Merged prep kernel: four independent jobs dispatched by blockIdx.x range.
//   [0, 576)      pad+transpose+f16 convert (LDS-transpose, coalesced both sides)
//   [576, 3024)   weight transform OIHW f32 -> [row][tap*128+ci] f16
//   [3024, 3325)  border zero of 24 padded buffer-images + guard rows
//   [3325, 3343)  flow-guided offset adds
// ---------------------------------------------------------------------------
__global__ __launch_bounds__(256) void prep_kernel(
    const float* __restrict__ q, const float* __restrict__ f,
    _Float16* __restrict__ xq, _Float16* __restrict__ xf,
    const float* __restrict__ wv, const float* __restrict__ wo,
    const float* __restrict__ wa, const float* __restrict__ wu,
    _Float16* __restrict__ wt,
    const float* __restrict__ ff, const float* __restrict__ fb,
    float* __restrict__ adds,
    _Float16* __restrict__ wsh) {
  __shared__ _Float16 plds[48 * 136];      // [px][c], stride 136: bank decorrelation
  const int b = blockIdx.x;
  const int tid = threadIdx.x;

  if (b < 576) {
    // ---- pad_convert: one block per (buf, img, image-row) ----
    const int buf = b / 288;
    const int rem = b - buf * 288;
    const int img = rem / 48, y = rem - img * 48;
    const float* src = buf ? f : q;
    _Float16* dst = buf ? xf : xq;

    const int c = tid >> 1;                // channel 0..127
    const int seg = tid & 1;               // pixel half: 0..23 / 24..47
    const float* rowp = src + ((size_t)img * 128 + c) * HW + y * WID + seg * 24;
    f32x4 v[6];
#pragma unroll
    for (int k = 0; k < 6; ++k) v[k] = *(const f32x4*)(rowp + 4 * k);
#pragma unroll
    for (int k = 0; k < 6; ++k)
#pragma unroll
      for (int e = 0; e < 4; ++e)
        plds[(seg * 24 + 4 * k + e) * 136 + c] = (_Float16)v[k][e];
    __syncthreads();

    _Float16* dstp = dst + (((size_t)img * PAD + y + 1) * PAD + 1) * 128;
#pragma unroll
    for (int k = 0; k < 3; ++k) {
      int m = tid + 256 * k;               // chunk 0..767
      int px = m >> 4, c0 = (m & 15) << 3;
      half8 h = *(const half8*)(plds + px * 136 + c0);
      *(half8*)(dstp + (size_t)m * 8) = h;
    }

  } else if (b < 3024) {
    // ---- weight transform ----
    int gi = (b - 576) * 256 + tid;
    if (gi >= 544 * 1152) return;
    int row = gi / 1152, k = gi - row * 1152;
    int tap = k >> 7, ci = k & 127;
    const float* src; int co;
    if (row < 128)      { src = wv; co = row; }
    else if (row < 320) { src = wo; co = row - 128; }
    else if (row < 416) { src = wa; co = row - 320; }
    else                { src = wu; co = row - 416; }
    wt[gi] = (_Float16)src[((size_t)co * 128 + ci) * 9 + tap];

  } else if (b < 3325) {
    // ---- border zero ----
    int gi = (b - 3024) * 256 + tid;
    const int IMG_ELE = PAD * PAD * 128;     // 320000 halfs per padded image
    half8 z = {};
    if (gi < 75264) {
      int bi = gi / 3136;                    // buffer-image 0..23
      int r = gi - bi * 3136;
      int p = r >> 4;                        // border pixel 0..195
      int cc = (r & 15) << 3;                // half offset within 128
      int y, x;
      if (p < 50)       { y = 0;           x = p; }
      else if (p < 100) { y = 49;          x = p - 50; }
      else if (p < 148) { y = p - 100 + 1; x = 0; }
      else              { y = p - 148 + 1; x = 49; }
      *(half8*)(wsh + (size_t)bi * IMG_ELE + ((size_t)y * PAD + x) * 128 + cc) = z;
    } else if (gi < 76864) {
      int r = gi - 75264;                    // guard: 2 rows of 50 px
      *(half8*)(wsh + (size_t)24 * IMG_ELE + (size_t)r * 8) = z;
    }

  } else {
    // ---- flow adds ----
    int idx = (b - 3325) * 256 + tid;
    if (idx >= 2 * HW) return;
    int n = idx / HW, hw = idx - n * HW;
    int y = hw / WID, x = hw - y * WID;

    const float* F = ff + (size_t)n * 4 * HW;
    const float* B = fb + (size_t)n * 4 * HW;

    float ff01x = F[hw],          ff01y = F[HW + hw];
    float ff12x = F[2 * HW + hw], ff12y = F[3 * HW + hw];
    float fb10x = B[hw],          fb10y = B[HW + hw];
    float fb21x = B[2 * HW + hw], fb21y = B[3 * HW + hw];

    auto warp2 = [&](const float* cx, const float* cy, float flox, float floy,
                     float& ox, float& oy) {
      float sx = (float)x + flox, sy = (float)y + floy;
      float fx = floorf(sx), fy = floorf(sy);
      int x0 = (int)fx, y0 = (int)fy;
      float wx = sx - fx, wy = sy - fy;
      float w00 = (1.f - wx) * (1.f - wy), w10 = wx * (1.f - wy);
      float w01 = (1.f - wx) * wy,         w11 = wx * wy;
      auto inside = [](int xi, int yi) {
        return (xi >= 0 && xi <= WID - 1 && yi >= 0 && yi <= WID - 1) ? 1.f : 0.f;
      };
      float m = w00 * inside(x0, y0)     + w10 * inside(x0 + 1, y0) +
                w01 * inside(x0, y0 + 1) + w11 * inside(x0 + 1, y0 + 1);
      float mm = (m < 0.999f) ? 0.f : 1.f;
      auto cl = [](int v) { return v < 0 ? 0 : (v > WID - 1 ? WID - 1 : v); };
      int xa = cl(x0), xb = cl(x0 + 1), ya = cl(y0), yb = cl(y0 + 1);
      int i00 = ya * WID + xa, i10 = ya * WID + xb;
      int i01 = yb * WID + xa, i11 = yb * WID + xb;
      ox = mm * (w00 * cx[i00] + w10 * cx[i10] + w01 * cx[i01] + w11 * cx[i11]);
      oy = mm * (w00 * cy[i00] + w10 * cy[i10] + w01 * cy[i01] + w11 * cy[i11]);
    };

    float wfx, wfy;
    warp2(F + 2 * HW, F + 3 * HW, ff01x, ff01y, wfx, wfy);
    float ff02x = ff01x + wfx, ff02y = ff01y + wfy;
    float wbx, wby;
    warp2(B, B + HW, fb21x, fb21y, wbx, wby);
    float fb20x = fb21x + wbx, fb20y = fb21y + wby;

    auto W_ = [&](int t, int l, float vx, float vy) {
      size_t o = (((size_t)(n * 3 + t) * 3 + l) * HW + hw) * 2;
      adds[o] = vx; adds[o + 1] = vy;
    };
    W_(0, 0, 0.f, 0.f);     W_(0, 1, ff01x, ff01y); W_(0, 2, ff02x, ff02y);
    W_(1, 0, fb10x, fb10y); W_(1, 1, 0.f, 0.f);     W_(1, 2, ff12x, ff12y);
    W_(2, 0, fb20x, fb20y); W_(2, 1, fb21x, fb21y); W_(2, 2, 0.f, 0.f);
  }
}

// ---------------------------------------------------------------------------
// MFMA implicit-GEMM conv body, 2-deep COUNTED-VMCNT pipeline, RACE-HARDENED:
// every s_barrier is inline-asm with a "memory" clobber (the builtin is
// IntrNoMem -- NOT a compiler fence -- so ds_reads of the next stage could
// be hoisted above the barrier past another wave's still-in-flight
// global_load_lds; that was the r14 flaky divergence). sched_barrier(0)
// brackets pin the machine scheduler as well (rule #18). Waitcnt protocol
// unchanged: vmcnt(5) keeps 5 loads in flight across the barrier.
// 2 buffers x 20KB keeps 3 blocks/CU.
// ---------------------------------------------------------------------------
#define CONV_BUF_ELE (96 * 64 + 64 * 64)   // 10240 halfs per buffer

__device__ __forceinline__ void conv_body(
    int bx, const _Float16* __restrict__ xpad, const _Float16* __restrict__ wt,
    const float* __restrict__ bias0, const float* __restrict__ bias1, int bsplit,
    int CO, int co0, int layout, void* __restrict__ outp, _Float16* lds) {
  const int tid = threadIdx.x;
  const int w = tid >> 6, lane = tid & 63;
  const int img = bx / 24, rp = bx - img * 24;
  const int y0 = rp * 2;

  const int pxh = w & 1, coh = w >> 1;

  f32x4 acc[3][2] = {};

  const int lr8 = lane >> 3;               // 0..7
  const int lc  = lane & 7;                // chunk 0..7

  // stage s: 5 global_load_lds per wave (3 A + 2 B) into buffer l
  auto stage = [&](int s, _Float16* l) {
    const int tap = s >> 1, ci0 = (s & 1) << 6;
    const int dy = tap / 3, dx = tap - dy * 3;
    _Float16* lA = l;
    _Float16* lB = l + 96 * 64;
#pragma unroll
    for (int it = 0; it < 3; ++it) {
      int i = w * 3 + it;
      int r = 8 * i + lr8;                 // px row 0..95
      int cs = lc ^ (r & 7);
      int up = (r >= 48) ? 1 : 0;
      int yy = y0 + up + dy;
      int xx = (r - 48 * up) + dx;
      const _Float16* src = xpad + (((size_t)(img * PAD + yy)) * PAD + xx) * 128 + ci0 + cs * 8;
      gload_lds16(src, lA + i * 512);
    }
#pragma unroll
    for (int jt = 0; jt < 2; ++jt) {
      int j = w * 2 + jt;
      int r = 8 * j + lr8;                 // co row 0..63
      int cs = lc ^ (r & 7);
      int co = co0 + r; if (co >= CO) co = CO - 1;
      const _Float16* src = wt + (size_t)co * 1152 + tap * 128 + ci0 + cs * 8;
      gload_lds16(src, lB + j * 512);
    }
  };

  // prologue: stages 0 and 1 in flight; wait only stage 0 (own 5 oldest)
  stage(0, lds);
  stage(1, lds + CONV_BUF_ELE);
  asm volatile("s_waitcnt vmcnt(5)" ::: "memory");
  asm volatile("s_barrier" ::: "memory");
  __builtin_amdgcn_sched_barrier(0);

  const int lrow = lane & 15, lk = lane >> 4;
#pragma unroll
  for (int s = 0; s < 18; ++s) {
    _Float16* lA = lds + (s & 1) * CONV_BUF_ELE;   // static (unrolled)
    _Float16* lB = lA + 96 * 64;

    __builtin_amdgcn_s_setprio(1);
#pragma unroll
    for (int sub = 0; sub < 2; ++sub) {
      int kc = sub * 4 + lk;               // chunk 0..7
      half8 a[3], bb[2];
#pragma unroll
      for (int m = 0; m < 3; ++m) {
        int r = 48 * pxh + 16 * m + lrow;
        a[m] = *(const half8*)(lA + r * 64 + ((kc ^ (r & 7)) * 8));
      }
#pragma unroll
      for (int n = 0; n < 2; ++n) {
        int r = 32 * coh + 16 * n + lrow;
        bb[n] = *(const half8*)(lB + r * 64 + ((kc ^ (r & 7)) * 8));
      }
#pragma unroll
      for (int m = 0; m < 3; ++m)
#pragma unroll
        for (int n = 0; n < 2; ++n)
          acc[m][n] = __builtin_amdgcn_mfma_f32_16x16x32_f16(a[m], bb[n], acc[m][n], 0, 0, 0);
    }
    __builtin_amdgcn_s_setprio(0);

    if (s < 17) {
      // barrier 1: all waves done READING buf(s&1). asm memory clobber makes
      // this a compiler fence (the builtin is NOT), so the stage(s+2) LDS
      // writes below cannot move above it.
      __builtin_amdgcn_sched_barrier(0);
      asm volatile("s_barrier" ::: "memory");
      if (s + 2 < 18) {
        stage(s + 2, lA);                  // overwrite buf(s&1) for stage s+2
        // wait own stage-(s+1) loads (5 oldest); s+2's 5 stay in flight
        asm volatile("s_waitcnt vmcnt(5)" ::: "memory");
      } else {
        asm volatile("s_waitcnt vmcnt(0)" ::: "memory");
      }
      // barrier 2: buf((s+1)&1) fully populated by ALL waves. Memory clobber
      // + sched_barrier stop next-stage ds_reads from hoisting above it
      // (this wave's vmcnt only covers its OWN loads -- r14's race).
      asm volatile("s_barrier" ::: "memory");
      __builtin_amdgcn_sched_barrier(0);
    }
  }

  // ---- epilogue (direct stores) ----
  const int lg = lane >> 4;
#pragma unroll
  for (int m = 0; m < 3; ++m) {
#pragma unroll
    for (int n = 0; n < 2; ++n) {
      int co = co0 + 32 * coh + 16 * n + lrow;
      if (co >= CO) continue;
      float bv = (co < bsplit) ? bias0[co] : bias1[co - bsplit];
#pragma unroll
      for (int r = 0; r < 4; ++r) {
        int pl = 48 * pxh + 16 * m + 4 * lg + r;   // 0..95
        int pix = rp * 96 + pl;
        float v = acc[m][n][r] + bv;
        if (layout == 1) {
          ((_Float16*)outp)[((size_t)img * HW + pix) * CO + co] = (_Float16)v;
        } else if (layout == 2) {
          int yy = pix / WID, xx = pix - yy * WID;
          ((_Float16*)outp)[(((size_t)img * PAD + yy + 1) * PAD + xx + 1) * 128 + co] = (_Float16)v;
        } else {
          ((float*)outp)[((size_t)img * CO + co) * HW + pix] = v;
        }
      }
    }
  }
}

// Merged offattn conv (blockIdx.y 0..4) + value conv (blockIdx.y 5..6).
__global__ __launch_bounds__(256) void conv_offattn_value(
    const _Float16* __restrict__ xq, const _Float16* __restrict__ xf,
    const _Float16* __restrict__ wt,
    const float* __restrict__ b_off, const float* __restrict__ b_attn,
    const float* __restrict__ b_val,
    _Float16* __restrict__ offattn, _Float16* __restrict__ vpad) {
  __shared__ _Float16 lds[2 * CONV_BUF_ELE];
  const int y = blockIdx.y;
  if (y < 5) {
    conv_body(blockIdx.x, xq, wt + (size_t)128 * 1152, b_off, b_attn, 192,
              288, y * 64, 1, offattn, lds);
  } else {
    conv_body(blockIdx.x, xf, wt, b_val, b_val, 128,
              128, (y - 5) * 64, 2, vpad, lds);
  }
}

// Final conv: f32 NCHW out.
__global__ __launch_bounds__(256) void conv_out(
    const _Float16* __restrict__ xout, const _Float16* __restrict__ wt,
    const float* __restrict__ b_out, float* __restrict__ out) {
  __shared__ _Float16 lds[2 * CONV_BUF_ELE];
  conv_body(blockIdx.x, xout, wt, b_out, b_out, 128, 128, blockIdx.y * 64, 0,
            out, lds);
}

// ---------------------------------------------------------------------------
// Sampling + softmax + attention-weighted sum, 16-lane cooperative groups.
// Per-point broadcast via LDS (ds_read same-address broadcast, conflict-free)
// ---------------------------------------------------------------------------
__global__ __launch_bounds__(256) void sample_kernel(
    const _Float16* __restrict__ vpad,     // [6][50][50][128] padded values
    const _Float16* __restrict__ offattn,  // [6][hw][288] (192 off + 96 attn)
    const float* __restrict__ refpts, const float* __restrict__ adds,
    _Float16* __restrict__ xout) {
  __shared__ float Wlds[16][13][4];        // [group][point(13=pad)][w00,w10,w01,w11]
  __shared__ int   IBlds[16][12];
  const int tid = threadIdx.x;
  const int pixg = blockIdx.x * 2 + (tid >> 7);
  const int g = tid >> 4;                  // group 0..15
  const int h = g & 7;
  const int d = tid & 15;
  const int img = pixg / HW, hw = pixg - img * HW;
  const int n = img / 3, t = img - n * 3;

  const _Float16* rec = offattn + ((size_t)img * HW + hw) * 288;

  // -------- phase 1: lane i computes sampling data for point i --------
  const int i = (d < 12) ? d : 11;         // lanes 12-15 duplicate point 11
  const int l = i >> 2;                    // level

  half2 o2 = *(const half2*)(rec + (h * 12 + i) * 2);
  float lgt = (float)rec[192 + h * 12 + i];
  if (d >= 12) lgt = -1e30f;

  const float* addp = adds + (((size_t)(n * 3 + t) * 3 + l) * HW + hw) * 2;
  const float* rp = refpts + ((size_t)(n * 3 + t) * HW + hw) * 6 + l * 2;

  // px = (refx + ox/48)*48 - 0.5  ==  refx*48 - 0.5 + ox   (exact algebra)
  float px = fmaf(rp[0], 48.f, -0.5f) + (float)o2[0] + addp[0];
  float py = fmaf(rp[1], 48.f, -0.5f) + (float)o2[1] + addp[1];
  // clamp into padded-border range: reproduces zeros_pad masking exactly
  px = fminf(fmaxf(px, -1.f), 48.f);
  py = fminf(fmaxf(py, -1.f), 48.f);
  float fx = floorf(px), fy = floorf(py);
  int x0 = (int)fx, y0 = (int)fy;
  float wx = px - fx, wy = py - fy;
  float w00 = (1.f - wx) * (1.f - wy), w10 = wx * (1.f - wy);
  float w01 = (1.f - wx) * wy,         w11 = wx * wy;

  // softmax over the 12 points of this (pix,h), reduced across the group
  float mx = lgt;
#pragma unroll
  for (int m = 8; m >= 1; m >>= 1) mx = fmaxf(mx, __shfl_xor(mx, m, 16));
  float e = __expf(lgt - mx);              // lanes 12-15 -> exp(-huge) = 0
  float s = e;
#pragma unroll
  for (int m = 8; m >= 1; m >>= 1) s += __shfl_xor(s, m, 16);
  float aw = e * __builtin_amdgcn_rcpf(s);
  w00 *= aw; w10 *= aw; w01 *= aw; w11 *= aw;

  // corner base index (f16 elements) into padded value image (n*3 + l)
  int ib = (((n * 3 + l) * PAD + (y0 + 1)) * PAD + (x0 + 1)) * 128 + h * 16;

  // stage per-point data to LDS (lanes 12-15 must NOT write)
  if (d < 12) {
    f32x4 w4 = {w00, w10, w01, w11};
    *(f32x4*)&Wlds[g][d][0] = w4;
    IBlds[g][d] = ib;
  }
  __syncthreads();

  // -------- phase 2: every lane gathers its channel for all 12 points ----
  float acc = 0.f;
#pragma unroll
  for (int j = 0; j < 12; ++j) {
    f32x4 W = *(const f32x4*)&Wlds[g][j][0];   // broadcast read
    int jb = IBlds[g][j];
    const _Float16* vp = vpad + jb + d;
    acc = fmaf(W[0], (float)vp[0], acc);
    acc = fmaf(W[1], (float)vp[128], acc);
    acc = fmaf(W[2], (float)vp[PAD * 128], acc);
    acc = fmaf(W[3], (float)vp[PAD * 128 + 128], acc);
  }

  int y = hw / WID, x = hw - y * WID;
  xout[(((size_t)img * PAD + y + 1) * PAD + x + 1) * 128 + h * 16 + d] = (_Float16)acc;
}

// ---------------------------------------------------------------------------
extern "C" void kernel_launch(void* const* d_in, const int* in_sizes, int n_in,
                              void* d_out, int out_size, void* d_ws, size_t ws_size,
                              hipStream_t stream) {
  const float* query         = (const float*)d_in[0];
  const float* input_flatten = (const float*)d_in[1];
  const float* refpts        = (const float*)d_in[2];
  const float* ff            = (const float*)d_in[3];
  const float* fb            = (const float*)d_in[4];
  const float* w_off         = (const float*)d_in[5];
  const float* b_off         = (const float*)d_in[6];
  const float* w_attn        = (const float*)d_in[7];
  const float* b_attn        = (const float*)d_in[8];
  const float* w_val         = (const float*)d_in[9];
  const float* b_val         = (const float*)d_in[10];
  const float* w_out         = (const float*)d_in[11];
  const float* b_out         = (const float*)d_in[12];
  float* out = (float*)d_out;

  char* ws = (char*)d_ws;
  const size_t PADSZ = (size_t)6 * PAD * PAD * 128 * sizeof(_Float16);  // 3,840,000
  const size_t GUARD = (size_t)2 * PAD * 128 * sizeof(_Float16);        // 25,600
  _Float16* xq      = (_Float16*)(ws);
  _Float16* xf      = (_Float16*)(ws + PADSZ);
  _Float16* xout    = (_Float16*)(ws + 2 * PADSZ);
  _Float16* vpad    = (_Float16*)(ws + 3 * PADSZ);                      // padded values
  _Float16* wt      = (_Float16*)(ws + 4 * PADSZ + GUARD);              // 544*1152*2
  _Float16* offattn = (_Float16*)(ws + 4 * PADSZ + GUARD + 1253376);    // 6*2304*288*2
  float*    adds    = (float*)   (ws + 4 * PADSZ + GUARD + 1253376 + 7962624);

  // 1: all independent prep work (pad/convert, weights, border zero, flow)
  prep_kernel<<<3343, 256, 0, stream>>>(query, input_flatten, xq, xf,
                                        w_val, w_off, w_attn, w_out, wt,
                                        ff, fb, adds, (_Float16*)ws);

  // 2: merged off+attn conv (y 0..4, CO=288, f16 pixel-major) and
  //    value conv (y 5..6, CO=128, f16 padded pixel-major)
  conv_offattn_value<<<dim3(144, 7), 256, 0, stream>>>(xq, xf, wt,
                                                       b_off, b_attn, b_val,
                                                       offattn, vpad);

  // 3: sampling + softmax + weighted sum
  sample_kernel<<<6912, 256, 0, stream>>>(vpad, offattn, refpts, adds, xout);

  // 4: final conv, f32 NCHW out
  conv_out<<<dim3(144, 2), 256, 0, stream>>>(xout, wt + (size_t)416 * 1152,
                                             b_out, out);
}